// Round 1
// baseline (236.356 us; speedup 1.0000x reference)
//
#include <hip/hip_runtime.h>
#include <cmath>

#define HE 361
#define WE 720
#define LL 37
#define HM 180
#define WM 360
#define KK 32
#define NPTS (HM * WM)
#define EPSF 1e-8f
#define PTSB 8   // model points per block; 360 % 8 == 0 -> block never crosses a row

// out layout: out3d [HM*WM*KK*5] | p_model [HM*WM*KK] | ps_o [HM*WM]
#define OFF1 ((size_t)HM * WM * KK * 5)
#define OFF2 (OFF1 + (size_t)HM * WM * KK)

// ws layout (float units):
#define WS_IY    0
#define WS_TY    180
#define WS_IX    360
#define WS_TX    720
#define WS_LOGPE 1080

__device__ __forceinline__ int upper_bound_g(const float* a, int n, float v) {
    int lo = 0, hi = n;
    while (lo < hi) {
        int m = (lo + hi) >> 1;
        if (a[m] <= v) lo = m + 1; else hi = m;
    }
    return lo;  // searchsorted side='right'
}

__global__ void precompute_kernel(const float* __restrict__ era5_lat,
                                  const float* __restrict__ era5_lon,
                                  const float* __restrict__ model_lat,
                                  const float* __restrict__ model_lon,
                                  const float* __restrict__ p_levels,
                                  int* __restrict__ ws_iy, float* __restrict__ ws_ty,
                                  int* __restrict__ ws_ix, float* __restrict__ ws_tx,
                                  float* __restrict__ ws_logpe) {
    int t = blockIdx.x * blockDim.x + threadIdx.x;
    if (t < HM) {
        float v = model_lat[t];
        int i = upper_bound_g(era5_lat, HE, v) - 1;
        if (i < 0) i = 0;
        if (i > HE - 2) i = HE - 2;
        ws_iy[t] = i;
        ws_ty[t] = (v - era5_lat[i]) / (era5_lat[i + 1] - era5_lat[i]);
    } else if (t < HM + WM) {
        int j = t - HM;
        float v = model_lon[j];
        int i = upper_bound_g(era5_lon, WE, v) - 1;
        if (i < 0) i = 0;
        if (i > WE - 2) i = WE - 2;
        ws_ix[j] = i;
        ws_tx[j] = (v - era5_lon[i]) / (era5_lon[i + 1] - era5_lon[i]);
    } else if (t < HM + WM + LL) {
        int k = t - HM - WM;
        ws_logpe[k] = logf(p_levels[k] + EPSF);
    }
}

// Fused kernel: block of 256 threads handles PTSB=8 model points.
// Phase 1: horizontal bilinear for 8*185 channels -> LDS (24 loads in flight/thread).
// Phase 2: vertical log-p interpolation from LDS -> out (coalesced stores).
__global__ void __launch_bounds__(256)
fused_kernel(const float* __restrict__ u, const float* __restrict__ v,
             const float* __restrict__ w, const float* __restrict__ T,
             const float* __restrict__ q, const float* __restrict__ ps,
             const float* __restrict__ p_levels,
             const float* __restrict__ a_k, const float* __restrict__ b_k,
             const int* __restrict__ ws_iy, const float* __restrict__ ws_ty,
             const int* __restrict__ ws_ix, const float* __restrict__ ws_tx,
             const float* __restrict__ ws_logpe,
             float* __restrict__ out) {
    __shared__ float s_h[PTSB][5 * LL];   // 8 x 185; stride 185 % 32 = 25 -> conflict-free
    __shared__ float s_psm[PTSB];
    __shared__ int   s_maxi[PTSB];        // max(nvalid-2, 0)
    __shared__ int   s_inval[PTSB];       // nvalid < 2
    __shared__ float s_logpe[LL];
    __shared__ float s_ak[KK];
    __shared__ float s_bk[KK];

    const int tid = threadIdx.x;
    if (tid < LL) {
        s_logpe[tid] = ws_logpe[tid];
    } else if (tid >= 64 && tid < 64 + KK) {
        s_ak[tid - 64] = a_k[tid - 64];
        s_bk[tid - 64] = b_k[tid - 64];
    }

    const int pt_local = tid >> 5;          // 0..7
    const int grp      = tid & 31;          // 0..31
    const int pt = blockIdx.x * PTSB + pt_local;
    const int y  = pt / WM;
    const int x  = pt - y * WM;

    const int   iy = ws_iy[y];
    const float ty = ws_ty[y];
    const int   ix = ws_ix[x];
    const float tx = ws_tx[x];
    const float omty = 1.0f - ty;
    const float omtx = 1.0f - tx;

    const size_t b00 = (size_t)iy * WE + ix;

    if (grp == 0) {
        const float p00 = ps[b00], p01 = ps[b00 + 1];
        const float p10 = ps[b00 + WE], p11 = ps[b00 + WE + 1];
        const float ps_m = omty * (omtx * p00 + tx * p01) + ty * (omtx * p10 + tx * p11);
        s_psm[pt_local] = ps_m;
        // nvalid = # of p_levels <= ps_m (searchsorted side='right'); once per point
        const int nvalid = upper_bound_g(p_levels, LL, ps_m);
        int maxi = nvalid - 2;
        if (maxi < 0) maxi = 0;
        s_maxi[pt_local]  = maxi;
        s_inval[pt_local] = (nvalid < 2) ? 1 : 0;
        out[OFF2 + pt] = fminf(fmaxf(ps_m, 30000.0f), 110000.0f);
    }

    const float* srcs0 = u;
    const float* srcs1 = v;
    const float* srcs2 = w;
    const float* srcs3 = T;
    const float* srcs4 = q;

#pragma unroll
    for (int it = 0; it < 6; it++) {
        const int ch = grp + 32 * it;
        if (ch < 5 * LL) {
            const int var = ch / LL;
            const int l   = ch - var * LL;
            const float* s = (var == 0) ? srcs0 : (var == 1) ? srcs1
                           : (var == 2) ? srcs2 : (var == 3) ? srcs3 : srcs4;
            const size_t c00 = b00 * LL + l;
            const float d00 = s[c00];
            const float d01 = s[c00 + LL];
            const float d10 = s[c00 + (size_t)WE * LL];
            const float d11 = s[c00 + (size_t)WE * LL + LL];
            s_h[pt_local][ch] = omty * (omtx * d00 + tx * d01) +
                                ty   * (omtx * d10 + tx * d11);
        }
    }

    __syncthreads();

    // Phase 2: thread = (pt_local, k)
    const int k = grp;
    const float ps_m = s_psm[pt_local];
    const int   maxi = s_maxi[pt_local];
    const bool  invalid = (s_inval[pt_local] != 0);

    const float pm = s_ak[k] + s_bk[k] * ps_m;
    out[OFF1 + (size_t)pt * KK + k] = pm;

    const float lpm = logf(pm + EPSF);
    int lo = 0, hi = LL;
    while (lo < hi) {
        int m = (lo + hi) >> 1;
        if (s_logpe[m] <= lpm) lo = m + 1; else hi = m;
    }
    int i = lo - 1;
    if (i < 0) i = 0;
    if (i > maxi) i = maxi;
    const float t = (lpm - s_logpe[i]) / (s_logpe[i + 1] - s_logpe[i]);

    const size_t obase = (size_t)pt * (KK * 5) + k * 5;
#pragma unroll
    for (int var = 0; var < 5; var++) {
        const float g0 = s_h[pt_local][var * LL + i];
        const float g1 = s_h[pt_local][var * LL + i + 1];
        float o = g0 + t * (g1 - g0);
        if (invalid) o = 0.0f;                       // zero BEFORE clip (matches ref)
        if (var == 3) o = fminf(fmaxf(o, 150.0f), 350.0f);
        if (var == 4) o = fminf(fmaxf(o, 0.0f), 0.05f);
        out[obase + var] = o;
    }
}

extern "C" void kernel_launch(void* const* d_in, const int* in_sizes, int n_in,
                              void* d_out, int out_size, void* d_ws, size_t ws_size,
                              hipStream_t stream) {
    const float* u         = (const float*)d_in[0];
    const float* v         = (const float*)d_in[1];
    const float* w         = (const float*)d_in[2];
    const float* T         = (const float*)d_in[3];
    const float* q         = (const float*)d_in[4];
    const float* ps        = (const float*)d_in[5];
    const float* era5_lat  = (const float*)d_in[6];
    const float* era5_lon  = (const float*)d_in[7];
    const float* model_lat = (const float*)d_in[8];
    const float* model_lon = (const float*)d_in[9];
    const float* p_levels  = (const float*)d_in[10];
    const float* a_k       = (const float*)d_in[11];
    const float* b_k       = (const float*)d_in[12];

    float* wsf = (float*)d_ws;
    int*   ws_iy    = (int*)(wsf + WS_IY);
    float* ws_ty    = wsf + WS_TY;
    int*   ws_ix    = (int*)(wsf + WS_IX);
    float* ws_tx    = wsf + WS_TX;
    float* ws_logpe = wsf + WS_LOGPE;

    float* out = (float*)d_out;

    precompute_kernel<<<3, 256, 0, stream>>>(era5_lat, era5_lon, model_lat, model_lon,
                                             p_levels, ws_iy, ws_ty, ws_ix, ws_tx,
                                             ws_logpe);

    const int blocks = NPTS / PTSB;   // 8100
    fused_kernel<<<blocks, 256, 0, stream>>>(u, v, w, T, q, ps, p_levels, a_k, b_k,
                                             ws_iy, ws_ty, ws_ix, ws_tx, ws_logpe, out);
}

// Round 2
// 232.918 us; speedup vs baseline: 1.0148x; 1.0148x over previous
//
#include <hip/hip_runtime.h>
#include <cmath>

#define HE 361
#define WE 720
#define LL 37
#define HM 180
#define WM 360
#define KK 32
#define NPTS (HM * WM)
#define EPSF 1e-8f
#define PTSB 8   // model points per block; 360 % 8 == 0 -> block never crosses a row
#define WE37 (WE * LL)

// out layout: out3d [HM*WM*KK*5] | p_model [HM*WM*KK] | ps_o [HM*WM]
#define OFF1 ((size_t)HM * WM * KK * 5)
#define OFF2 (OFF1 + (size_t)HM * WM * KK)

// ws layout (float units):
#define WS_IY    0
#define WS_TY    180
#define WS_IX    360
#define WS_TX    720
#define WS_LOGPE 1080

__device__ __forceinline__ int upper_bound_g(const float* a, int n, float v) {
    int lo = 0, hi = n;
    while (lo < hi) {
        int m = (lo + hi) >> 1;
        if (a[m] <= v) lo = m + 1; else hi = m;
    }
    return lo;  // searchsorted side='right'
}

__global__ void precompute_kernel(const float* __restrict__ era5_lat,
                                  const float* __restrict__ era5_lon,
                                  const float* __restrict__ model_lat,
                                  const float* __restrict__ model_lon,
                                  const float* __restrict__ p_levels,
                                  int* __restrict__ ws_iy, float* __restrict__ ws_ty,
                                  int* __restrict__ ws_ix, float* __restrict__ ws_tx,
                                  float* __restrict__ ws_logpe) {
    int t = blockIdx.x * blockDim.x + threadIdx.x;
    if (t < HM) {
        float v = model_lat[t];
        int i = upper_bound_g(era5_lat, HE, v) - 1;
        if (i < 0) i = 0;
        if (i > HE - 2) i = HE - 2;
        ws_iy[t] = i;
        ws_ty[t] = (v - era5_lat[i]) / (era5_lat[i + 1] - era5_lat[i]);
    } else if (t < HM + WM) {
        int j = t - HM;
        float v = model_lon[j];
        int i = upper_bound_g(era5_lon, WE, v) - 1;
        if (i < 0) i = 0;
        if (i > WE - 2) i = WE - 2;
        ws_ix[j] = i;
        ws_tx[j] = (v - era5_lon[i]) / (era5_lon[i + 1] - era5_lon[i]);
    } else if (t < HM + WM + LL) {
        int k = t - HM - WM;
        ws_logpe[k] = logf(p_levels[k] + EPSF);
    }
}

// Fully wave-synchronous fused kernel: NO __syncthreads().
// Each 64-lane wave owns 2 model points (lanes 0-31 -> pt 2w, lanes 32-63 -> pt 2w+1).
// All LDS producer/consumer pairs are within one wave (in-order LDS pipe).
// Phase 1: 24 global loads issued up-front into registers (full MLP), bilinear -> s_h.
// Phase 2: vertical log-p interp; results staged in s_out, flushed with coalesced stores.
__global__ void __launch_bounds__(256)
fused_kernel(const float* __restrict__ u, const float* __restrict__ v,
             const float* __restrict__ w, const float* __restrict__ T,
             const float* __restrict__ q, const float* __restrict__ ps,
             const float* __restrict__ p_levels,
             const float* __restrict__ a_k, const float* __restrict__ b_k,
             const int* __restrict__ ws_iy, const float* __restrict__ ws_ty,
             const int* __restrict__ ws_ix, const float* __restrict__ ws_tx,
             const float* __restrict__ ws_logpe,
             float* __restrict__ out) {
    __shared__ float s_h[PTSB][5 * LL];   // per-point horizontal interp result
    __shared__ float s_psm[PTSB];
    __shared__ int   s_maxi[PTSB];
    __shared__ int   s_inval[PTSB];
    __shared__ float s_logpe[4][LL];      // per-wave copy (no cross-wave traffic)
    __shared__ float s_out[4][2 * KK * 5];// per-wave store-coalescing buffer

    const int tid      = threadIdx.x;
    const int wv       = tid >> 6;        // wave id 0..3
    const int lane     = tid & 63;
    const int pt_local = tid >> 5;        // 0..7
    const int grp      = tid & 31;        // channel-lane / k

    // per-wave table load (lanes 0..36)
    if (lane < LL) s_logpe[wv][lane] = ws_logpe[lane];

    const int y  = (blockIdx.x * PTSB) / WM;           // uniform per block
    const int x0 = blockIdx.x * PTSB - y * WM;         // uniform per block
    const int x  = x0 + pt_local;
    const int pt = blockIdx.x * PTSB + pt_local;

    const int   iy = ws_iy[y];     // scalar (uniform)
    const float ty = ws_ty[y];
    const int   ix = ws_ix[x];
    const float tx = ws_tx[x];
    const float omty = 1.0f - ty;
    const float omtx = 1.0f - tx;

    const int b00  = iy * WE + ix;          // < 260k, fits int
    const int base = b00 * LL;              // < 9.62M, fits int
    const int i0   = base + grp;            // row iy,  col ix,  level grp (grp<32<37: valid)
    const int i1   = base + grp + WE37;     // row iy+1

    // ---- Phase 1 loads: all 24 issued before any use (MLP) ----
    float a00[5], a01[5], a10[5], a11[5];
#define LD4(slot, S) \
    a00[slot] = S[i0];      a01[slot] = S[i0 + LL]; \
    a10[slot] = S[i1];      a11[slot] = S[i1 + LL];
    LD4(0, u) LD4(1, v) LD4(2, w) LD4(3, T) LD4(4, q)
#undef LD4

    // tail: 25 channels (var 0..4, level 32..36) handled by grp<25
    const bool tval = (grp < 25);
    int tvar = grp / 5;
    int tl   = 32 + (grp - tvar * 5);
    if (!tval) { tvar = 0; tl = 32; }       // safe dummy load
    const float* ts = (tvar == 0) ? u : (tvar == 1) ? v
                    : (tvar == 2) ? w : (tvar == 3) ? T : q;
    const int ti0 = base + tl;
    const int ti1 = base + tl + WE37;
    const float t00 = ts[ti0], t01 = ts[ti0 + LL];
    const float t10 = ts[ti1], t11 = ts[ti1 + LL];

    // early per-thread coefficient loads (L2-hot)
    const float ak = a_k[grp];
    const float bk = b_k[grp];

    // ---- ps_m + nvalid: one lane per point; overlaps the d-load latency ----
    if (grp == 0) {
        const float p00 = ps[b00], p01 = ps[b00 + 1];
        const float p10 = ps[b00 + WE], p11 = ps[b00 + WE + 1];
        const float ps_m = omty * (omtx * p00 + tx * p01) + ty * (omtx * p10 + tx * p11);
        s_psm[pt_local] = ps_m;
        const int nvalid = upper_bound_g(p_levels, LL, ps_m);   // exact, matches ref
        int maxi = nvalid - 2;
        if (maxi < 0) maxi = 0;
        s_maxi[pt_local]  = maxi;
        s_inval[pt_local] = (nvalid < 2) ? 1 : 0;
        out[OFF2 + pt] = fminf(fmaxf(ps_m, 30000.0f), 110000.0f);
    }

    // ---- bilinear -> s_h (writer group == reader group: wave-synchronous) ----
#pragma unroll
    for (int it = 0; it < 5; it++) {
        const float hv = omty * (omtx * a00[it] + tx * a01[it]) +
                         ty   * (omtx * a10[it] + tx * a11[it]);
        s_h[pt_local][it * LL + grp] = hv;
    }
    {
        const float hv = omty * (omtx * t00 + tx * t01) + ty * (omtx * t10 + tx * t11);
        if (tval) s_h[pt_local][tvar * LL + tl] = hv;
    }

    // ---- Phase 2: thread = (pt_local, k) ----
    const int   k       = grp;
    const float ps_m    = s_psm[pt_local];
    const int   maxi    = s_maxi[pt_local];
    const bool  invalid = (s_inval[pt_local] != 0);

    const float pm = ak + bk * ps_m;
    out[OFF1 + (size_t)pt * KK + k] = pm;   // coalesced per 32-lane group

    const float lpm = logf(pm + EPSF);
    int lo = 0, hi = LL;
    while (lo < hi) {
        int m = (lo + hi) >> 1;
        if (s_logpe[wv][m] <= lpm) lo = m + 1; else hi = m;
    }
    int i = lo - 1;
    if (i < 0) i = 0;
    if (i > maxi) i = maxi;
    const float t = (lpm - s_logpe[wv][i]) / (s_logpe[wv][i + 1] - s_logpe[wv][i]);

    // results into per-wave staging buffer (stride-5 writes: gcd(5,32)=1 -> conflict-free)
    const int half = lane >> 5;             // 0/1 within wave
    float* so = &s_out[wv][half * (KK * 5)];
#pragma unroll
    for (int var = 0; var < 5; var++) {
        const float g0 = s_h[pt_local][var * LL + i];
        const float g1 = s_h[pt_local][var * LL + i + 1];
        float o = g0 + t * (g1 - g0);
        if (invalid) o = 0.0f;                       // zero BEFORE clip (matches ref)
        if (var == 3) o = fminf(fmaxf(o, 150.0f), 350.0f);
        if (var == 4) o = fminf(fmaxf(o, 0.0f), 0.05f);
        so[k * 5 + var] = o;
    }

    __builtin_amdgcn_wave_barrier();        // compile-time ordering fence (no-op HW)

    // ---- coalesced flush: wave's 2 points = 320 contiguous floats ----
    const size_t ob = (size_t)(blockIdx.x * PTSB + 2 * wv) * (KK * 5);
#pragma unroll
    for (int c = 0; c < 5; c++) {
        out[ob + lane + 64 * c] = s_out[wv][lane + 64 * c];
    }
}

extern "C" void kernel_launch(void* const* d_in, const int* in_sizes, int n_in,
                              void* d_out, int out_size, void* d_ws, size_t ws_size,
                              hipStream_t stream) {
    const float* u         = (const float*)d_in[0];
    const float* v         = (const float*)d_in[1];
    const float* w         = (const float*)d_in[2];
    const float* T         = (const float*)d_in[3];
    const float* q         = (const float*)d_in[4];
    const float* ps        = (const float*)d_in[5];
    const float* era5_lat  = (const float*)d_in[6];
    const float* era5_lon  = (const float*)d_in[7];
    const float* model_lat = (const float*)d_in[8];
    const float* model_lon = (const float*)d_in[9];
    const float* p_levels  = (const float*)d_in[10];
    const float* a_k       = (const float*)d_in[11];
    const float* b_k       = (const float*)d_in[12];

    float* wsf = (float*)d_ws;
    int*   ws_iy    = (int*)(wsf + WS_IY);
    float* ws_ty    = wsf + WS_TY;
    int*   ws_ix    = (int*)(wsf + WS_IX);
    float* ws_tx    = wsf + WS_TX;
    float* ws_logpe = wsf + WS_LOGPE;

    float* out = (float*)d_out;

    precompute_kernel<<<3, 256, 0, stream>>>(era5_lat, era5_lon, model_lat, model_lon,
                                             p_levels, ws_iy, ws_ty, ws_ix, ws_tx,
                                             ws_logpe);

    const int blocks = NPTS / PTSB;   // 8100
    fused_kernel<<<blocks, 256, 0, stream>>>(u, v, w, T, q, ps, p_levels, a_k, b_k,
                                             ws_iy, ws_ty, ws_ix, ws_tx, ws_logpe, out);
}